// Round 8
// baseline (1010.699 us; speedup 1.0000x reference)
//
#include <hip/hip_runtime.h>
#include <hip/hip_cooperative_groups.h>
namespace cg = cooperative_groups;

// N=2048, D=512, A=64, NQ=8, G1=G2=8, A1=128.
// Algebra (no softmax): ctx = q (K^T V)/sqrt(a) => per-group fold:
//   S[g]=(xWk+bk)^T(xWv+bv)/sqrt(a); M[g]=sum_q Wq S Wo_q; o[g]=x M[g]+c[g];
//   tier2 same; Wo2p[g]=Wo2[g]@Wo precomputed => M2p = T2@Wo2p,
//   c2p = r2@Wo2p + (bo2@Wo + bo).
// R8: R7's one-cooperative-kernel plan, but with UNIONED shared memory.
// R7 failed because per-helper static __shared__ SUMS (~35KB/block) ->
// runtime occupancy 1 block/CU -> coop launch of 512 rejected (output never
// written, absmax == ref max). Now one 16KB smem buffer serves all helpers
// (entry __syncthreads in each since they alias). Fallback ladder:
// coop512 -> coop256 -> 13 plain per-stage launches (==R6, guaranteed pass).

typedef __bf16 bf16x8 __attribute__((ext_vector_type(8)));
typedef float  f32x4  __attribute__((ext_vector_type(4)));

struct PD { const float* s; void* d; int R, C, Bc, mode, blocks; };
struct PArgs { PD p[20]; int n; };

struct MA {
    const float *x,*bq1,*bo1,*bq2,*bo2,*bo;
    float* out;
    __bf16 *xb,*Wk1t,*Wv1t,*Wq1b,*Wo1t,*Wk2t,*Wv2t,*Wq2b,*Wo2b,*Wot;
    __bf16 *Ktb,*Vtb,*STb1,*T1b,*M1t,*o1b,*K2tb,*V2tb,*STb2,*T2b,*Wo2pT,*M2pt;
    float *STf1,*STf2,*kvb1,*kvb2,*c1,*c2p,*bo2p;
    PArgs pa;
    int prepTot;
};

// ---------------- bf16 MFMA GEMM block, C = alpha*(A.B^T) (+bias) ----------
// A: bf16 [M][K] lda; B: bf16 [N][K] ldb (k-major). bz = b*ksplit+ks;
// b -> (go=b/divq, gi=b%divq). mode: 0=f32, 1=bf16, 2=bf16 transposed
// (C[n][m], ldc=M), 3=f32 atomicAdd. Dims are exact tile multiples.
// smem: As at sm[0], Bs at sm[BM*64] (BM*32 bf16 each).
template<int BM, int BN>
__device__ __forceinline__ void gemm_block(void* smv,
    const __bf16* __restrict__ A, const __bf16* __restrict__ B,
    const float* __restrict__ bias, void* __restrict__ Cv,
    int K, int lda, int ldb, int ldc, int divq, int ksplit,
    long aOut, long aIn, long bOut, long bIn, long cOut, long cIn,
    long biasOut, long biasIn, int hasBias, int mode, float alpha,
    int bx, int by, int bz)
{
    constexpr int MT = BM / 32, NT = BN / 32;
    __bf16 (*As)[32] = (__bf16(*)[32])smv;
    __bf16 (*Bs)[32] = (__bf16(*)[32])((char*)smv + BM * 64);

    int b  = bz / ksplit, ks = bz - b * ksplit;
    int go = b / divq,  gi = b - go * divq;
    A += go * aOut + gi * aIn;
    B += go * bOut + gi * bIn;
    long cBase = go * cOut + gi * cIn;
    if (hasBias) bias += go * biasOut + gi * biasIn;

    int kChunk = K / ksplit;
    int k0 = ks * kChunk, kEnd = k0 + kChunk;

    int bm = by * BM, bn = bx * BN;
    int tid = threadIdx.x, wave = tid >> 6, lane = tid & 63;
    int wm = (wave >> 1) * (BM / 2), wn = (wave & 1) * (BN / 2);
    int mrow = lane & 15, quad = lane >> 4;

    f32x4 acc[MT][NT];
    #pragma unroll
    for (int i = 0; i < MT; ++i)
        #pragma unroll
        for (int j = 0; j < NT; ++j)
            acc[i][j] = f32x4{0.f, 0.f, 0.f, 0.f};

    for (; k0 < kEnd; k0 += 32) {
        __syncthreads();   // prev smem consumers done before overwrite
        #pragma unroll
        for (int t = 0; t < BM / 64; ++t) {
            int c = tid + t * 256;
            int row = c >> 2, kq = c & 3;
            __builtin_amdgcn_global_load_lds(
                (const __attribute__((address_space(1))) void*)
                    (A + (long)(bm + row) * lda + k0 + kq * 8),
                (__attribute__((address_space(3))) void*)&As[row][kq * 8],
                16, 0, 0);
        }
        #pragma unroll
        for (int t = 0; t < BN / 64; ++t) {
            int c = tid + t * 256;
            int row = c >> 2, kq = c & 3;
            __builtin_amdgcn_global_load_lds(
                (const __attribute__((address_space(1))) void*)
                    (B + (long)(bn + row) * ldb + k0 + kq * 8),
                (__attribute__((address_space(3))) void*)&Bs[row][kq * 8],
                16, 0, 0);
        }
        __syncthreads();

        bf16x8 af[MT], bfv[NT];
        #pragma unroll
        for (int mt = 0; mt < MT; ++mt)
            af[mt] = *(const bf16x8*)&As[wm + mt * 16 + mrow][quad * 8];
        #pragma unroll
        for (int nt = 0; nt < NT; ++nt)
            bfv[nt] = *(const bf16x8*)&Bs[wn + nt * 16 + mrow][quad * 8];
        #pragma unroll
        for (int mt = 0; mt < MT; ++mt)
            #pragma unroll
            for (int nt = 0; nt < NT; ++nt)
                acc[mt][nt] = __builtin_amdgcn_mfma_f32_16x16x32_bf16(
                    af[mt], bfv[nt], acc[mt][nt], 0, 0, 0);
    }

    #pragma unroll
    for (int mt = 0; mt < MT; ++mt) {
        #pragma unroll
        for (int r = 0; r < 4; ++r) {
            int row = bm + wm + mt * 16 + quad * 4 + r;
            #pragma unroll
            for (int nt = 0; nt < NT; ++nt) {
                int col = bn + wn + nt * 16 + mrow;
                float v = acc[mt][nt][r] * alpha;
                if (hasBias) v += bias[col];
                if (mode == 0)
                    ((float*)Cv)[cBase + (long)row * ldc + col] = v;
                else if (mode == 1)
                    ((__bf16*)Cv)[cBase + (long)row * ldc + col] = (__bf16)v;
                else if (mode == 2)
                    ((__bf16*)Cv)[cBase + (long)col * ldc + row] = (__bf16)v;
                else
                    atomicAdd(&((float*)Cv)[cBase + (long)row * ldc + col], v);
            }
        }
    }
}

// ---------------- prep block: converts/transposes/zeros ---------------------
__device__ __forceinline__ void prep_block(const PArgs& a, int bid, void* smv)
{
    int i = 0;
    while (i < a.n && bid >= a.p[i].blocks) { bid -= a.p[i].blocks; ++i; }
    if (i >= a.n) return;
    PD d = a.p[i];
    int t = threadIdx.x;
    if (d.mode == 0) {
        float (*tile)[33] = (float(*)[33])smv;
        __syncthreads();   // aliased smem
        int tC = d.C >> 5, tR = d.R >> 5;
        int batch = bid / (tC * tR), rem = bid - batch * (tC * tR);
        int tyo = rem / tC, txo = rem - tyo * tC;
        const float* src = d.s + (long)batch * d.R * d.C;
        __bf16* dst = (__bf16*)d.d + (long)batch * d.R * d.C;
        int tx = t & 31, ty = t >> 5;
        int r0 = tyo * 32, c0 = txo * 32;
        #pragma unroll
        for (int u = 0; u < 4; ++u)
            tile[ty + 8 * u][tx] = src[(long)(r0 + ty + 8 * u) * d.C + c0 + tx];
        __syncthreads();
        #pragma unroll
        for (int u = 0; u < 4; ++u)
            dst[(long)(c0 + ty + 8 * u) * d.R + r0 + tx] = (__bf16)tile[tx][ty + 8 * u];
        __syncthreads();
    } else if (d.mode == 1) {
        long idx = ((long)bid * 256 + t) * 4;
        long total = (long)d.Bc * d.R * d.C;
        if (idx < total) {
            float4 f = *(const float4*)(d.s + idx);
            __bf16* o = (__bf16*)d.d + idx;
            o[0] = (__bf16)f.x; o[1] = (__bf16)f.y;
            o[2] = (__bf16)f.z; o[3] = (__bf16)f.w;
        }
    } else {
        long idx = (long)bid * 256 + t;
        long total = (long)d.Bc * d.R * d.C;
        if (idx < total) {
            float* o = (float*)d.d;
            if (d.mode == 2) o[idx] = d.s[idx];
            else             o[idx] = 0.f;
        }
    }
}

// ---------------- small block: conv(STf->STb) + fused r,c -------------------
__device__ __forceinline__ void small_block(void* smv,
    const float* __restrict__ STf, __bf16* __restrict__ STb,
    const float* __restrict__ bq, const __bf16* __restrict__ WoT,
    const float* __restrict__ boA, float* __restrict__ cOut,
    int ad, int F, int nConv, long nS, long wG, int bid)
{
    int tid = threadIdx.x;
    if (bid < nConv) {
        long idx = ((long)bid * 256 + tid) * 4;
        if (idx < nS) {
            float4 f = *(const float4*)(STf + idx);
            __bf16* o = STb + idx;
            o[0] = (__bf16)f.x; o[1] = (__bf16)f.y;
            o[2] = (__bf16)f.z; o[3] = (__bf16)f.w;
        }
        return;
    }
    float* rL  = (float*)smv;                    // F floats (<=4096B)
    float* red = (float*)((char*)smv + 4096);    // 256 floats
    __syncthreads();   // aliased smem
    int b2 = bid - nConv;
    int g = b2 >> 5, slice = b2 & 31;
    int nq = F / ad;
    const float* Sg = STf + (long)g * ad * ad;
    for (int f = tid; f < F; f += 256) {
        int q = f / ad, aa = f - q * ad;
        const float* bv = bq + (long)(g * nq + q) * ad;
        const float* Sa = Sg + (long)aa * ad;
        float s = 0.f;
        for (int c = 0; c < ad; c += 4) {
            float4 b4 = *(const float4*)(bv + c);
            float4 s4 = *(const float4*)(Sa + c);
            s += b4.x * s4.x + b4.y * s4.y + b4.z * s4.z + b4.w * s4.w;
        }
        rL[f] = s;
    }
    __syncthreads();
    int dl = tid & 15, fs = tid >> 4;
    int d = slice * 16 + dl;
    int fchunk = F >> 4;
    const __bf16* wrow = WoT + (long)g * wG + (long)d * F;
    float s = 0.f;
    for (int f0 = fs * fchunk; f0 < (fs + 1) * fchunk; f0 += 8) {
        bf16x8 w = *(const bf16x8*)(wrow + f0);
        s += rL[f0]     * (float)w[0] + rL[f0 + 1] * (float)w[1]
           + rL[f0 + 2] * (float)w[2] + rL[f0 + 3] * (float)w[3]
           + rL[f0 + 4] * (float)w[4] + rL[f0 + 5] * (float)w[5]
           + rL[f0 + 6] * (float)w[6] + rL[f0 + 7] * (float)w[7];
    }
    red[tid] = s;
    __syncthreads();
    if (fs == 0) {
        float tsum = s;
        #pragma unroll
        for (int u = 1; u < 16; ++u) tsum += red[u * 16 + dl];
        cOut[(long)g * 512 + d] = boA[(long)g * 512 + d] + tsum;
    }
}

// outp[g][d] = bias[d] + sum_f v[g][f] * WT[d][f]   (F=512)
__device__ __forceinline__ void vecmat_block(void* smv,
    const float* __restrict__ v, const __bf16* __restrict__ WT,
    const float* __restrict__ bias, float* __restrict__ outp, int g, int slice)
{
    float* red2 = (float*)smv;
    __syncthreads();   // aliased smem
    int tid = threadIdx.x;
    int dl = tid & 15, fs = tid >> 4;
    int d = slice * 16 + dl;
    const float* vg = v + (long)g * 512;
    const __bf16* wrow = WT + (long)d * 512;
    float s = 0.f;
    for (int f0 = fs * 32; f0 < (fs + 1) * 32; f0 += 8) {
        bf16x8 w = *(const bf16x8*)(wrow + f0);
        s += vg[f0]     * (float)w[0] + vg[f0 + 1] * (float)w[1]
           + vg[f0 + 2] * (float)w[2] + vg[f0 + 3] * (float)w[3]
           + vg[f0 + 4] * (float)w[4] + vg[f0 + 5] * (float)w[5]
           + vg[f0 + 6] * (float)w[6] + vg[f0 + 7] * (float)w[7];
    }
    red2[tid] = s;
    __syncthreads();
    if (fs == 0) {
        float tsum = s;
        #pragma unroll
        for (int u = 1; u < 16; ++u) tsum += red2[u * 16 + dl];
        outp[(long)g * 512 + d] = bias[d] + tsum;
    }
}

// ---------------- one stage of the pipeline ---------------------------------
__device__ __forceinline__ void run_stage(const MA& a, int s, int vb, void* sm)
{
    const float isa1 = 0.08838834764831845f;  // 1/sqrt(128)
    switch (s) {
    case 0: prep_block(a.pa, vb, sm); break;
    case 1:   // KV1 (1024) | Wo2p = Wo2@Wo (512) | bo2p (256)
        if (vb < 1024)
            gemm_block<64,64>(sm, a.xb, a.Wk1t, a.kvb1, a.Ktb, 512, 512, 512, 2048,
                1, 1, 0L, 0L, 65536L, 0L, 262144L, 0L, 128L, 0L, 1, 2, 1.0f,
                vb & 1, (vb >> 1) & 31, vb >> 6);
        else if (vb < 1536) {
            int v = vb - 1024;
            gemm_block<64,64>(sm, a.Wo2b, a.Wot, nullptr, a.Wo2pT, 512, 512, 512, 512,
                1, 1, 262144L, 0L, 0L, 0L, 262144L, 0L, 0L, 0L, 0, 2, 1.0f,
                v & 7, (v >> 3) & 7, v >> 6);
        } else {
            int v = vb - 1536;
            vecmat_block(sm, a.bo2, a.Wot, a.bo, a.bo2p, v & 7, v >> 3);
        }
        break;
    case 2:   // S1^T split-K x8 atomic (256)
        gemm_block<64,64>(sm, a.Vtb, a.Ktb, nullptr, a.STf1, 2048, 2048, 2048, 128,
            1, 8, 262144L, 0L, 262144L, 0L, 16384L, 0L, 0L, 0L, 0, 3, isa1,
            vb & 1, (vb >> 1) & 1, vb >> 2);
        break;
    case 3:   // small1 (384)
        small_block(sm, a.STf1, a.STb1, a.bq1, a.Wo1t, a.bo1, a.c1,
                    128, 1024, 128, 131072L, 524288L, vb);
        break;
    case 4:   // T1 (1024)
        gemm_block<64,64>(sm, a.Wq1b, a.STb1, nullptr, a.T1b, 128, 128, 128, 1024,
            8, 1, 524288L, 65536L, 16384L, 0L, 524288L, 128L, 0L, 0L, 0, 1, 1.0f,
            vb & 1, (vb >> 1) & 7, vb >> 4);
        break;
    case 5:   // M1^T (512)
        gemm_block<64,64>(sm, a.T1b, a.Wo1t, nullptr, a.M1t, 1024, 1024, 1024, 512,
            1, 1, 524288L, 0L, 524288L, 0L, 262144L, 0L, 0L, 0L, 0, 2, 1.0f,
            vb & 7, (vb >> 3) & 7, vb >> 6);
        break;
    case 6:   // o1 = x.M1 + c1 (512, 128^2)
        gemm_block<128,128>(sm, a.xb, a.M1t, a.c1, a.o1b, 512, 512, 512, 512,
            1, 1, 0L, 0L, 262144L, 0L, 1048576L, 0L, 512L, 0L, 1, 1, 1.0f,
            vb & 3, (vb >> 2) & 15, vb >> 6);
        break;
    case 7:   // KV2 fused (512)
        gemm_block<64,64>(sm, a.o1b, a.Wk2t, a.kvb2, a.K2tb, 512, 512, 512, 2048,
            8, 1, 0L, 1048576L, 262144L, 32768L, 1048576L, 131072L, 512L, 64L,
            1, 2, 1.0f, 0, vb & 31, vb >> 5);
        break;
    case 8:   // S2^T split-K x16 atomic (128)
        gemm_block<64,64>(sm, a.V2tb, a.K2tb, nullptr, a.STf2, 2048, 2048, 2048, 64,
            1, 16, 131072L, 0L, 131072L, 0L, 4096L, 0L, 0L, 0L, 0, 3, 0.125f,
            0, 0, vb);
        break;
    case 9:   // small2 -> c2p via Wo2pT/bo2p (288)
        small_block(sm, a.STf2, a.STb2, a.bq2, a.Wo2pT, a.bo2p, a.c2p,
                    64, 512, 32, 32768L, 262144L, vb);
        break;
    case 10:  // T2 (512)
        gemm_block<64,64>(sm, a.Wq2b, a.STb2, nullptr, a.T2b, 64, 64, 64, 512,
            8, 1, 262144L, 32768L, 4096L, 0L, 262144L, 64L, 0L, 0L, 0, 1, 1.0f,
            0, vb & 7, vb >> 3);
        break;
    case 11:  // M2p^T = (T2.Wo2p)^T (512)
        gemm_block<64,64>(sm, a.T2b, a.Wo2pT, nullptr, a.M2pt, 512, 512, 512, 512,
            1, 1, 262144L, 0L, 262144L, 0L, 262144L, 0L, 0L, 0L, 0, 2, 1.0f,
            vb & 7, (vb >> 3) & 7, vb >> 6);
        break;
    default:  // 12: out = o1.M2p + c2p (512, 128^2)
        gemm_block<128,128>(sm, a.o1b, a.M2pt, a.c2p, a.out, 512, 512, 512, 512,
            1, 1, 1048576L, 0L, 262144L, 0L, 1048576L, 0L, 512L, 0L, 1, 0, 1.0f,
            vb & 3, (vb >> 2) & 15, vb >> 6);
        break;
    }
}

__global__ __launch_bounds__(256, 2) void mega(MA a)
{
    __shared__ __align__(16) unsigned char smem[16384];
    cg::grid_group grid = cg::this_grid();
    const int GD = gridDim.x;
    int counts[13] = {a.prepTot, 1792, 256, 384, 1024, 512, 512, 512, 128, 288,
                      512, 512, 512};
    for (int s = 0; s < 13; ++s) {
        for (int vb = blockIdx.x; vb < counts[s]; vb += GD)
            run_stage(a, s, vb, smem);
        if (s < 12) grid.sync();
    }
}

__global__ __launch_bounds__(256, 2) void stage_kernel(MA a, int stage)
{
    __shared__ __align__(16) unsigned char smem[16384];
    run_stage(a, stage, blockIdx.x, smem);
}

extern "C" void kernel_launch(void* const* d_in, const int* in_sizes, int n_in,
                              void* d_out, int out_size, void* d_ws, size_t ws_size,
                              hipStream_t stream)
{
    MA ma;
    ma.x   = (const float*)d_in[0];
    const float* Wq1 = (const float*)d_in[1];  ma.bq1 = (const float*)d_in[2];
    const float* Wk1 = (const float*)d_in[3];  const float* bk1 = (const float*)d_in[4];
    const float* Wv1 = (const float*)d_in[5];  const float* bv1 = (const float*)d_in[6];
    const float* Wo1 = (const float*)d_in[7];  ma.bo1 = (const float*)d_in[8];
    const float* Wq2 = (const float*)d_in[9];  ma.bq2 = (const float*)d_in[10];
    const float* Wk2 = (const float*)d_in[11]; const float* bk2 = (const float*)d_in[12];
    const float* Wv2 = (const float*)d_in[13]; const float* bv2 = (const float*)d_in[14];
    const float* Wo2 = (const float*)d_in[15]; ma.bo2 = (const float*)d_in[16];
    const float* Wo  = (const float*)d_in[17]; ma.bo  = (const float*)d_in[18];
    ma.out = (float*)d_out;
    (void)in_sizes; (void)n_in; (void)out_size; (void)ws_size;

    __bf16* wb = (__bf16*)d_ws;
    long o = 0;
    ma.xb    = wb + o; o += 1048576;
    ma.Wk1t  = wb + o; o += 524288;
    ma.Wv1t  = wb + o; o += 524288;
    ma.Wq1b  = wb + o; o += 4194304;
    ma.Wo1t  = wb + o; o += 4194304;
    ma.Wk2t  = wb + o; o += 262144;
    ma.Wv2t  = wb + o; o += 262144;
    ma.Wq2b  = wb + o; o += 2097152;
    ma.Wo2b  = wb + o; o += 2097152;   // Wo2 bf16 flat [g][512f][512d]
    ma.Wot   = wb + o; o += 262144;    // Wo^T [512e][512d]
    ma.Ktb   = wb + o; o += 2097152;   // K1^T [g][128][2048]
    ma.Vtb   = wb + o; o += 2097152;
    ma.STb1  = wb + o; o += 131072;
    ma.T1b   = wb + o; o += 4194304;
    ma.M1t   = wb + o; o += 2097152;
    ma.o1b   = wb + o; o += 8388608;
    ma.K2tb  = ma.Ktb;                 // alias: K2^T [g][64][2048]
    ma.V2tb  = ma.Ktb + 1048576;       // alias: V2^T
    ma.STb2  = wb + o; o += 32768;
    ma.T2b   = wb + o; o += 2097152;
    ma.Wo2pT = wb + o; o += 2097152;   // (Wo2@Wo)^T [g][512e][512f]
    ma.M2pt  = wb + o; o += 2097152;
    float* wf = (float*)(wb + o);
    long p = 0;
    ma.STf1 = wf + p; p += 131072;
    ma.STf2 = wf + p; p += 32768;
    ma.kvb1 = wf + p; p += 2048;
    ma.kvb2 = wf + p; p += 1024;
    ma.c1   = wf + p; p += 4096;
    ma.c2p  = wf + p; p += 4096;
    ma.bo2p = wf + p; p += 4096;

    int nd = 0, totB = 0;
    auto add = [&](const float* s, void* d, int R, int C, int Bc, int mode) {
        int blocks;
        long total = (long)Bc * R * C;
        if (mode == 0) blocks = Bc * (R >> 5) * (C >> 5);
        else if (mode == 1) blocks = (int)(total / 1024);
        else blocks = (int)((total + 255) / 256);
        ma.pa.p[nd] = PD{s, d, R, C, Bc, mode, blocks};
        ++nd; totB += blocks;
    };
    add(ma.x, ma.xb,   2048, 512, 1, 1);
    add(Wq1,  ma.Wq1b, 512, 128, 64, 1);
    add(Wq2,  ma.Wq2b, 512, 64, 64, 1);
    add(Wo2,  ma.Wo2b, 512, 512, 8, 1);
    add(Wk1,  ma.Wk1t, 512, 128, 8, 0);
    add(Wv1,  ma.Wv1t, 512, 128, 8, 0);
    add(Wo1,  ma.Wo1t, 1024, 512, 8, 0);
    add(Wk2,  ma.Wk2t, 512, 64, 8, 0);
    add(Wv2,  ma.Wv2t, 512, 64, 8, 0);
    add(Wo,   ma.Wot,  512, 512, 1, 0);
    add(bk1,  ma.kvb1,        1, 1024, 1, 2);
    add(bv1,  ma.kvb1 + 1024, 1, 1024, 1, 2);
    add(bk2,  ma.kvb2,        1, 512, 1, 2);
    add(bv2,  ma.kvb2 + 512,  1, 512, 1, 2);
    add(nullptr, ma.STf1, 1, 131072, 1, 4);
    add(nullptr, ma.STf2, 1, 32768, 1, 4);
    ma.pa.n = nd;
    ma.prepTot = totB;

    void* kargs[] = { &ma };
    hipError_t err = hipLaunchCooperativeKernel((void*)mega, dim3(512), dim3(256),
                                                kargs, 0, stream);
    if (err != hipSuccess) {
        (void)hipGetLastError();   // clear sticky error, retry smaller grid
        err = hipLaunchCooperativeKernel((void*)mega, dim3(256), dim3(256),
                                         kargs, 0, stream);
    }
    if (err != hipSuccess) {
        (void)hipGetLastError();   // final fallback: 13 plain launches
        int counts[13] = {ma.prepTot, 1792, 256, 384, 1024, 512, 512, 512, 128,
                          288, 512, 512, 512};
        for (int s = 0; s < 13; ++s)
            stage_kernel<<<dim3(counts[s]), dim3(256), 0, stream>>>(ma, s);
    }
}

// Round 9
// 872.012 us; speedup vs baseline: 1.1590x; 1.1590x over previous
//
#include <hip/hip_runtime.h>

// N=2048, D=512, A=64, NQ=8, G1=G2=8, A1=128.
// Algebra (no softmax): ctx = q (K^T V)/sqrt(a) => per-group fold:
//   S[g]=(xWk+bk)^T(xWv+bv)/sqrt(a); M[g]=sum_q Wq S Wo_q; o[g]=x M[g]+c[g];
//   tier2 same; Wo2p[g]=Wo2[g]@Wo precomputed => M2p = T2@Wo2p,
//   c2p = r2@Wo2p + (bo2@Wo + bo).
// R9: cooperative mega-kernel kept (stage logic verified in R8, absmax 40),
// but cg::grid.sync() replaced with a 16-shard sense-reversing barrier with
// s_sleep backoff. R8 evidence: grid.sync ~50us each (single-cacheline RMW
// x512 + hot spin => +100MB phantom FETCH). Also: T1/T2 stage B directly
// from fp32 S (convert-in-staging) => conv passes gone, 13 -> 11 stages,
// 10 barriers. Barrier state zeroed via hipMemsetAsync (capture-safe).

typedef __bf16 bf16x8 __attribute__((ext_vector_type(8)));
typedef float  f32x4  __attribute__((ext_vector_type(4)));

struct PD { const float* s; void* d; int R, C, Bc, mode, blocks; };
struct PArgs { PD p[20]; int n; };

struct MA {
    const float *x,*bq1,*bo1,*bq2,*bo2,*bo;
    float* out;
    __bf16 *xb,*Wk1t,*Wv1t,*Wq1b,*Wo1t,*Wk2t,*Wv2t,*Wq2b,*Wo2b,*Wot;
    __bf16 *Ktb,*Vtb,*T1b,*M1t,*o1b,*K2tb,*V2tb,*T2b,*Wo2pT,*M2pt;
    float *STf1,*STf2,*kvb1,*kvb2,*c1,*c2p,*bo2p;
    unsigned* bar;     // [shard i at i*16], master [256], gen [272]
    PArgs pa;
    int prepTot;
};

// ---- sharded grid barrier: 16 shards (64B apart) -> master -> gen flag ----
__device__ __forceinline__ void gbar(unsigned* bar, unsigned phase)
{
    __syncthreads();
    if (threadIdx.x == 0) {
        unsigned sh = blockIdx.x & 15;
        unsigned per = gridDim.x >> 4;
        unsigned old = __hip_atomic_fetch_add(&bar[sh * 16], 1u,
                           __ATOMIC_ACQ_REL, __HIP_MEMORY_SCOPE_AGENT);
        if (old == per - 1) {
            __hip_atomic_store(&bar[sh * 16], 0u, __ATOMIC_RELAXED,
                               __HIP_MEMORY_SCOPE_AGENT);
            unsigned o2 = __hip_atomic_fetch_add(&bar[256], 1u,
                              __ATOMIC_ACQ_REL, __HIP_MEMORY_SCOPE_AGENT);
            if (o2 == 15u) {
                __hip_atomic_store(&bar[256], 0u, __ATOMIC_RELAXED,
                                   __HIP_MEMORY_SCOPE_AGENT);
                __hip_atomic_fetch_add(&bar[272], 1u,
                    __ATOMIC_ACQ_REL, __HIP_MEMORY_SCOPE_AGENT);
            }
        }
        while (__hip_atomic_load(&bar[272], __ATOMIC_ACQUIRE,
                                 __HIP_MEMORY_SCOPE_AGENT) <= phase)
            __builtin_amdgcn_s_sleep(8);
    }
    __syncthreads();
}

// ---------------- bf16 MFMA GEMM block, C = alpha*(A.B^T) (+bias) ----------
// A: bf16 [M][K] lda (global_load_lds). B: [N][K] ldb k-major — bf16 via
// global_load_lds, or fp32 (BF32=true) converted during staging.
// bz = b*ksplit+ks; b -> (go=b/divq, gi=b%divq). mode: 0=f32, 1=bf16,
// 2=bf16 transposed (C[n][m], ldc=M), 3=f32 atomicAdd. Exact tile multiples.
template<int BM, int BN, bool BF32>
__device__ __forceinline__ void gemm_block(void* smv,
    const __bf16* __restrict__ A, const void* __restrict__ Bv,
    const float* __restrict__ bias, void* __restrict__ Cv,
    int K, int lda, int ldb, int ldc, int divq, int ksplit,
    long aOut, long aIn, long bOut, long bIn, long cOut, long cIn,
    long biasOut, long biasIn, int hasBias, int mode, float alpha,
    int bx, int by, int bz)
{
    constexpr int MT = BM / 32, NT = BN / 32;
    __bf16 (*As)[32] = (__bf16(*)[32])smv;
    __bf16 (*Bs)[32] = (__bf16(*)[32])((char*)smv + BM * 64);

    int b  = bz / ksplit, ks = bz - b * ksplit;
    int go = b / divq,  gi = b - go * divq;
    A += go * aOut + gi * aIn;
    const __bf16* Bb = (const __bf16*)Bv + (BF32 ? 0 : (go * bOut + gi * bIn));
    const float*  Bf = (const float*)Bv + (BF32 ? (go * bOut + gi * bIn) : 0);
    long cBase = go * cOut + gi * cIn;
    if (hasBias) bias += go * biasOut + gi * biasIn;

    int kChunk = K / ksplit;
    int k0 = ks * kChunk, kEnd = k0 + kChunk;

    int bm = by * BM, bn = bx * BN;
    int tid = threadIdx.x, wave = tid >> 6, lane = tid & 63;
    int wm = (wave >> 1) * (BM / 2), wn = (wave & 1) * (BN / 2);
    int mrow = lane & 15, quad = lane >> 4;

    f32x4 acc[MT][NT];
    #pragma unroll
    for (int i = 0; i < MT; ++i)
        #pragma unroll
        for (int j = 0; j < NT; ++j)
            acc[i][j] = f32x4{0.f, 0.f, 0.f, 0.f};

    for (; k0 < kEnd; k0 += 32) {
        __syncthreads();   // prev smem consumers done before overwrite
        #pragma unroll
        for (int t = 0; t < BM / 64; ++t) {
            int c = tid + t * 256;
            int row = c >> 2, kq = c & 3;
            __builtin_amdgcn_global_load_lds(
                (const __attribute__((address_space(1))) void*)
                    (A + (long)(bm + row) * lda + k0 + kq * 8),
                (__attribute__((address_space(3))) void*)&As[row][kq * 8],
                16, 0, 0);
        }
        if (!BF32) {
            #pragma unroll
            for (int t = 0; t < BN / 64; ++t) {
                int c = tid + t * 256;
                int row = c >> 2, kq = c & 3;
                __builtin_amdgcn_global_load_lds(
                    (const __attribute__((address_space(1))) void*)
                        (Bb + (long)(bn + row) * ldb + k0 + kq * 8),
                    (__attribute__((address_space(3))) void*)&Bs[row][kq * 8],
                    16, 0, 0);
            }
        } else {
            // BN=64: 256 threads x 8 fp32 -> bf16
            int row = tid >> 2, cb = (tid & 3) * 8;
            const float* src = Bf + (long)(bn + row) * ldb + k0 + cb;
            float4 f0 = *(const float4*)(src);
            float4 f1 = *(const float4*)(src + 4);
            bf16x8 v = {(__bf16)f0.x, (__bf16)f0.y, (__bf16)f0.z, (__bf16)f0.w,
                        (__bf16)f1.x, (__bf16)f1.y, (__bf16)f1.z, (__bf16)f1.w};
            *(bf16x8*)&Bs[row][cb] = v;
        }
        __syncthreads();

        bf16x8 af[MT], bfv[NT];
        #pragma unroll
        for (int mt = 0; mt < MT; ++mt)
            af[mt] = *(const bf16x8*)&As[wm + mt * 16 + mrow][quad * 8];
        #pragma unroll
        for (int nt = 0; nt < NT; ++nt)
            bfv[nt] = *(const bf16x8*)&Bs[wn + nt * 16 + mrow][quad * 8];
        #pragma unroll
        for (int mt = 0; mt < MT; ++mt)
            #pragma unroll
            for (int nt = 0; nt < NT; ++nt)
                acc[mt][nt] = __builtin_amdgcn_mfma_f32_16x16x32_bf16(
                    af[mt], bfv[nt], acc[mt][nt], 0, 0, 0);
    }

    #pragma unroll
    for (int mt = 0; mt < MT; ++mt) {
        #pragma unroll
        for (int r = 0; r < 4; ++r) {
            int row = bm + wm + mt * 16 + quad * 4 + r;
            #pragma unroll
            for (int nt = 0; nt < NT; ++nt) {
                int col = bn + wn + nt * 16 + mrow;
                float v = acc[mt][nt][r] * alpha;
                if (hasBias) v += bias[col];
                if (mode == 0)
                    ((float*)Cv)[cBase + (long)row * ldc + col] = v;
                else if (mode == 1)
                    ((__bf16*)Cv)[cBase + (long)row * ldc + col] = (__bf16)v;
                else if (mode == 2)
                    ((__bf16*)Cv)[cBase + (long)col * ldc + row] = (__bf16)v;
                else
                    atomicAdd(&((float*)Cv)[cBase + (long)row * ldc + col], v);
            }
        }
    }
}

// ---------------- prep block: converts/transposes/zeros ---------------------
__device__ __forceinline__ void prep_block(const PArgs& a, int bid, void* smv)
{
    int i = 0;
    while (i < a.n && bid >= a.p[i].blocks) { bid -= a.p[i].blocks; ++i; }
    if (i >= a.n) return;
    PD d = a.p[i];
    int t = threadIdx.x;
    if (d.mode == 0) {
        float (*tile)[33] = (float(*)[33])smv;
        __syncthreads();
        int tC = d.C >> 5, tR = d.R >> 5;
        int batch = bid / (tC * tR), rem = bid - batch * (tC * tR);
        int tyo = rem / tC, txo = rem - tyo * tC;
        const float* src = d.s + (long)batch * d.R * d.C;
        __bf16* dst = (__bf16*)d.d + (long)batch * d.R * d.C;
        int tx = t & 31, ty = t >> 5;
        int r0 = tyo * 32, c0 = txo * 32;
        #pragma unroll
        for (int u = 0; u < 4; ++u)
            tile[ty + 8 * u][tx] = src[(long)(r0 + ty + 8 * u) * d.C + c0 + tx];
        __syncthreads();
        #pragma unroll
        for (int u = 0; u < 4; ++u)
            dst[(long)(c0 + ty + 8 * u) * d.R + r0 + tx] = (__bf16)tile[tx][ty + 8 * u];
        __syncthreads();
    } else if (d.mode == 1) {
        long idx = ((long)bid * 256 + t) * 4;
        long total = (long)d.Bc * d.R * d.C;
        if (idx < total) {
            float4 f = *(const float4*)(d.s + idx);
            __bf16* o = (__bf16*)d.d + idx;
            o[0] = (__bf16)f.x; o[1] = (__bf16)f.y;
            o[2] = (__bf16)f.z; o[3] = (__bf16)f.w;
        }
    } else {
        long idx = (long)bid * 256 + t;
        long total = (long)d.Bc * d.R * d.C;
        if (idx < total) {
            float* o = (float*)d.d;
            if (d.mode == 2) o[idx] = d.s[idx];
            else             o[idx] = 0.f;
        }
    }
}

// ---------------- small block: fused r,c (c-only; S read as fp32) -----------
__device__ __forceinline__ void small_block(void* smv,
    const float* __restrict__ STf, const float* __restrict__ bq,
    const __bf16* __restrict__ WoT, const float* __restrict__ boA,
    float* __restrict__ cOut, int ad, int F, long wG, int bid)
{
    int tid = threadIdx.x;
    float* rL  = (float*)smv;
    float* red = (float*)((char*)smv + 4096);
    __syncthreads();
    int g = bid >> 5, slice = bid & 31;
    int nq = F / ad;
    const float* Sg = STf + (long)g * ad * ad;
    for (int f = tid; f < F; f += 256) {
        int q = f / ad, aa = f - q * ad;
        const float* bv = bq + (long)(g * nq + q) * ad;
        const float* Sa = Sg + (long)aa * ad;
        float s = 0.f;
        for (int c = 0; c < ad; c += 4) {
            float4 b4 = *(const float4*)(bv + c);
            float4 s4 = *(const float4*)(Sa + c);
            s += b4.x * s4.x + b4.y * s4.y + b4.z * s4.z + b4.w * s4.w;
        }
        rL[f] = s;
    }
    __syncthreads();
    int dl = tid & 15, fs = tid >> 4;
    int d = slice * 16 + dl;
    int fchunk = F >> 4;
    const __bf16* wrow = WoT + (long)g * wG + (long)d * F;
    float s = 0.f;
    for (int f0 = fs * fchunk; f0 < (fs + 1) * fchunk; f0 += 8) {
        bf16x8 w = *(const bf16x8*)(wrow + f0);
        s += rL[f0]     * (float)w[0] + rL[f0 + 1] * (float)w[1]
           + rL[f0 + 2] * (float)w[2] + rL[f0 + 3] * (float)w[3]
           + rL[f0 + 4] * (float)w[4] + rL[f0 + 5] * (float)w[5]
           + rL[f0 + 6] * (float)w[6] + rL[f0 + 7] * (float)w[7];
    }
    red[tid] = s;
    __syncthreads();
    if (fs == 0) {
        float tsum = s;
        #pragma unroll
        for (int u = 1; u < 16; ++u) tsum += red[u * 16 + dl];
        cOut[(long)g * 512 + d] = boA[(long)g * 512 + d] + tsum;
    }
}

// outp[g][d] = bias[d] + sum_f v[g][f] * WT[d][f]   (F=512)
__device__ __forceinline__ void vecmat_block(void* smv,
    const float* __restrict__ v, const __bf16* __restrict__ WT,
    const float* __restrict__ bias, float* __restrict__ outp, int g, int slice)
{
    float* red2 = (float*)smv;
    __syncthreads();
    int tid = threadIdx.x;
    int dl = tid & 15, fs = tid >> 4;
    int d = slice * 16 + dl;
    const float* vg = v + (long)g * 512;
    const __bf16* wrow = WT + (long)d * 512;
    float s = 0.f;
    for (int f0 = fs * 32; f0 < (fs + 1) * 32; f0 += 8) {
        bf16x8 w = *(const bf16x8*)(wrow + f0);
        s += vg[f0]     * (float)w[0] + vg[f0 + 1] * (float)w[1]
           + vg[f0 + 2] * (float)w[2] + vg[f0 + 3] * (float)w[3]
           + vg[f0 + 4] * (float)w[4] + vg[f0 + 5] * (float)w[5]
           + vg[f0 + 6] * (float)w[6] + vg[f0 + 7] * (float)w[7];
    }
    red2[tid] = s;
    __syncthreads();
    if (fs == 0) {
        float tsum = s;
        #pragma unroll
        for (int u = 1; u < 16; ++u) tsum += red2[u * 16 + dl];
        outp[(long)g * 512 + d] = bias[d] + tsum;
    }
}

// ---------------- stages 0..10 ----------------------------------------------
__device__ __forceinline__ void run_stage(const MA& a, int s, int vb, void* sm)
{
    const float isa1 = 0.08838834764831845f;  // 1/sqrt(128)
    switch (s) {
    case 0: prep_block(a.pa, vb, sm); break;
    case 1:   // KV1 (1024) | Wo2p (512) | bo2p (256)
        if (vb < 1024)
            gemm_block<64,64,false>(sm, a.xb, a.Wk1t, a.kvb1, a.Ktb,
                512, 512, 512, 2048, 1, 1,
                0L, 0L, 65536L, 0L, 262144L, 0L, 128L, 0L, 1, 2, 1.0f,
                vb & 1, (vb >> 1) & 31, vb >> 6);
        else if (vb < 1536) {
            int v = vb - 1024;
            gemm_block<64,64,false>(sm, a.Wo2b, a.Wot, nullptr, a.Wo2pT,
                512, 512, 512, 512, 1, 1,
                262144L, 0L, 0L, 0L, 262144L, 0L, 0L, 0L, 0, 2, 1.0f,
                v & 7, (v >> 3) & 7, v >> 6);
        } else {
            int v = vb - 1536;
            vecmat_block(sm, a.bo2, a.Wot, a.bo, a.bo2p, v & 7, v >> 3);
        }
        break;
    case 2:   // S1^T split-K x8 atomic (256)
        gemm_block<64,64,false>(sm, a.Vtb, a.Ktb, nullptr, a.STf1,
            2048, 2048, 2048, 128, 1, 8,
            262144L, 0L, 262144L, 0L, 16384L, 0L, 0L, 0L, 0, 3, isa1,
            vb & 1, (vb >> 1) & 1, vb >> 2);
        break;
    case 3:   // T1 from fp32 S (1024) | c1 (256)
        if (vb < 1024)
            gemm_block<64,64,true>(sm, a.Wq1b, a.STf1, nullptr, a.T1b,
                128, 128, 128, 1024, 8, 1,
                524288L, 65536L, 16384L, 0L, 524288L, 128L, 0L, 0L, 0, 1, 1.0f,
                vb & 1, (vb >> 1) & 7, vb >> 4);
        else
            small_block(sm, a.STf1, a.bq1, a.Wo1t, a.bo1, a.c1,
                        128, 1024, 524288L, vb - 1024);
        break;
    case 4:   // M1^T (512)
        gemm_block<64,64,false>(sm, a.T1b, a.Wo1t, nullptr, a.M1t,
            1024, 1024, 1024, 512, 1, 1,
            524288L, 0L, 524288L, 0L, 262144L, 0L, 0L, 0L, 0, 2, 1.0f,
            vb & 7, (vb >> 3) & 7, vb >> 6);
        break;
    case 5:   // o1 = x.M1 + c1 (512, 128^2)
        gemm_block<128,128,false>(sm, a.xb, a.M1t, a.c1, a.o1b,
            512, 512, 512, 512, 1, 1,
            0L, 0L, 262144L, 0L, 1048576L, 0L, 512L, 0L, 1, 1, 1.0f,
            vb & 3, (vb >> 2) & 15, vb >> 6);
        break;
    case 6:   // KV2 fused (512)
        gemm_block<64,64,false>(sm, a.o1b, a.Wk2t, a.kvb2, a.K2tb,
            512, 512, 512, 2048, 8, 1,
            0L, 1048576L, 262144L, 32768L, 1048576L, 131072L, 512L, 64L,
            1, 2, 1.0f, 0, vb & 31, vb >> 5);
        break;
    case 7:   // S2^T split-K x16 atomic (128)
        gemm_block<64,64,false>(sm, a.V2tb, a.K2tb, nullptr, a.STf2,
            2048, 2048, 2048, 64, 1, 16,
            131072L, 0L, 131072L, 0L, 4096L, 0L, 0L, 0L, 0, 3, 0.125f,
            0, 0, vb);
        break;
    case 8:   // T2 from fp32 S (512) | c2p (256)
        if (vb < 512)
            gemm_block<64,64,true>(sm, a.Wq2b, a.STf2, nullptr, a.T2b,
                64, 64, 64, 512, 8, 1,
                262144L, 32768L, 4096L, 0L, 262144L, 64L, 0L, 0L, 0, 1, 1.0f,
                0, vb & 7, vb >> 3);
        else
            small_block(sm, a.STf2, a.bq2, a.Wo2pT, a.bo2p, a.c2p,
                        64, 512, 262144L, vb - 512);
        break;
    case 9:   // M2p^T = (T2.Wo2p)^T (512)
        gemm_block<64,64,false>(sm, a.T2b, a.Wo2pT, nullptr, a.M2pt,
            512, 512, 512, 512, 1, 1,
            262144L, 0L, 262144L, 0L, 262144L, 0L, 0L, 0L, 0, 2, 1.0f,
            vb & 7, (vb >> 3) & 7, vb >> 6);
        break;
    default:  // 10: out = o1.M2p + c2p (512, 128^2)
        gemm_block<128,128,false>(sm, a.o1b, a.M2pt, a.c2p, a.out,
            512, 512, 512, 512, 1, 1,
            1048576L, 0L, 262144L, 0L, 1048576L, 0L, 512L, 0L, 1, 0, 1.0f,
            vb & 3, (vb >> 2) & 15, vb >> 6);
        break;
    }
}

__global__ __launch_bounds__(256, 2) void mega(MA a)
{
    __shared__ __align__(16) unsigned char smem[16384];
    const int GD = gridDim.x;
    const int counts[11] = {a.prepTot, 1792, 256, 1280, 512, 512, 512, 128,
                            768, 512, 512};
    unsigned phase = 0;
    #pragma unroll 1
    for (int s = 0; s < 11; ++s) {
        for (int vb = blockIdx.x; vb < counts[s]; vb += GD)
            run_stage(a, s, vb, smem);
        if (s < 10) gbar(a.bar, phase++);
    }
}

__global__ __launch_bounds__(256, 2) void stage_kernel(MA a, int stage)
{
    __shared__ __align__(16) unsigned char smem[16384];
    run_stage(a, stage, blockIdx.x, smem);
}

extern "C" void kernel_launch(void* const* d_in, const int* in_sizes, int n_in,
                              void* d_out, int out_size, void* d_ws, size_t ws_size,
                              hipStream_t stream)
{
    MA ma;
    ma.x   = (const float*)d_in[0];
    const float* Wq1 = (const float*)d_in[1];  ma.bq1 = (const float*)d_in[2];
    const float* Wk1 = (const float*)d_in[3];  const float* bk1 = (const float*)d_in[4];
    const float* Wv1 = (const float*)d_in[5];  const float* bv1 = (const float*)d_in[6];
    const float* Wo1 = (const float*)d_in[7];  ma.bo1 = (const float*)d_in[8];
    const float* Wq2 = (const float*)d_in[9];  ma.bq2 = (const float*)d_in[10];
    const float* Wk2 = (const float*)d_in[11]; const float* bk2 = (const float*)d_in[12];
    const float* Wv2 = (const float*)d_in[13]; const float* bv2 = (const float*)d_in[14];
    const float* Wo2 = (const float*)d_in[15]; ma.bo2 = (const float*)d_in[16];
    const float* Wo  = (const float*)d_in[17]; ma.bo  = (const float*)d_in[18];
    ma.out = (float*)d_out;
    (void)in_sizes; (void)n_in; (void)out_size; (void)ws_size;

    __bf16* wb = (__bf16*)d_ws;
    long o = 0;
    ma.xb    = wb + o; o += 1048576;
    ma.Wk1t  = wb + o; o += 524288;
    ma.Wv1t  = wb + o; o += 524288;
    ma.Wq1b  = wb + o; o += 4194304;
    ma.Wo1t  = wb + o; o += 4194304;
    ma.Wk2t  = wb + o; o += 262144;
    ma.Wv2t  = wb + o; o += 262144;
    ma.Wq2b  = wb + o; o += 2097152;
    ma.Wo2b  = wb + o; o += 2097152;   // Wo2 bf16 flat [g][512f][512d]
    ma.Wot   = wb + o; o += 262144;    // Wo^T [512e][512d]
    ma.Ktb   = wb + o; o += 2097152;   // K1^T [g][128][2048]
    ma.Vtb   = wb + o; o += 2097152;
    ma.T1b   = wb + o; o += 4194304;
    ma.M1t   = wb + o; o += 2097152;
    ma.o1b   = wb + o; o += 8388608;
    ma.K2tb  = ma.Ktb;                 // alias: K2^T [g][64][2048]
    ma.V2tb  = ma.Ktb + 1048576;       // alias: V2^T
    ma.T2b   = wb + o; o += 2097152;
    ma.Wo2pT = wb + o; o += 2097152;   // (Wo2@Wo)^T [g][512e][512f]
    ma.M2pt  = wb + o; o += 2097152;
    float* wf = (float*)(wb + o);
    long p = 0;
    ma.STf1 = wf + p; p += 131072;
    ma.STf2 = wf + p; p += 32768;
    ma.kvb1 = wf + p; p += 2048;
    ma.kvb2 = wf + p; p += 1024;
    ma.c1   = wf + p; p += 4096;
    ma.c2p  = wf + p; p += 4096;
    ma.bo2p = wf + p; p += 4096;
    ma.bar  = (unsigned*)(wf + p); p += 1024;   // 4KB barrier state

    int nd = 0, totB = 0;
    auto add = [&](const float* s, void* d, int R, int C, int Bc, int mode) {
        int blocks;
        long total = (long)Bc * R * C;
        if (mode == 0) blocks = Bc * (R >> 5) * (C >> 5);
        else if (mode == 1) blocks = (int)(total / 1024);
        else blocks = (int)((total + 255) / 256);
        ma.pa.p[nd] = PD{s, d, R, C, Bc, mode, blocks};
        ++nd; totB += blocks;
    };
    add(ma.x, ma.xb,   2048, 512, 1, 1);
    add(Wq1,  ma.Wq1b, 512, 128, 64, 1);
    add(Wq2,  ma.Wq2b, 512, 64, 64, 1);
    add(Wo2,  ma.Wo2b, 512, 512, 8, 1);
    add(Wk1,  ma.Wk1t, 512, 128, 8, 0);
    add(Wv1,  ma.Wv1t, 512, 128, 8, 0);
    add(Wo1,  ma.Wo1t, 1024, 512, 8, 0);
    add(Wk2,  ma.Wk2t, 512, 64, 8, 0);
    add(Wv2,  ma.Wv2t, 512, 64, 8, 0);
    add(Wo,   ma.Wot,  512, 512, 1, 0);
    add(bk1,  ma.kvb1,        1, 1024, 1, 2);
    add(bv1,  ma.kvb1 + 1024, 1, 1024, 1, 2);
    add(bk2,  ma.kvb2,        1, 512, 1, 2);
    add(bv2,  ma.kvb2 + 512,  1, 512, 1, 2);
    add(nullptr, ma.STf1, 1, 131072, 1, 4);
    add(nullptr, ma.STf2, 1, 32768, 1, 4);
    ma.pa.n = nd;
    ma.prepTot = totB;

    // zero barrier state (capture-safe; harness itself uses hipMemsetAsync)
    hipMemsetAsync(ma.bar, 0, 4096, stream);

    void* kargs[] = { &ma };
    hipError_t err = hipLaunchCooperativeKernel((void*)mega, dim3(512), dim3(256),
                                                kargs, 0, stream);
    if (err != hipSuccess) {
        (void)hipGetLastError();   // fallback: 11 plain launches
        int counts[11] = {ma.prepTot, 1792, 256, 1280, 512, 512, 512, 128,
                          768, 512, 512};
        for (int s = 0; s < 11; ++s)
            stage_kernel<<<dim3(counts[s]), dim3(256), 0, stream>>>(ma, s);
    }
}

// Round 10
// 303.158 us; speedup vs baseline: 3.3339x; 2.8764x over previous
//
#include <hip/hip_runtime.h>

// N=2048, D=512, A=64, NQ=8, G1=G2=8, A1=128.
// Algebra (no softmax): ctx = q (K^T V)/sqrt(a) => per-group fold:
//   S[g]=(xWk+bk)^T(xWv+bv)/sqrt(a); M[g]=sum_q Wq S Wo_q; o[g]=x M[g]+c[g];
//   tier2 same; Wo2p[g]=Wo2[g]@Wo precomputed => M2p = T2@Wo2p,
//   c2p = r2@Wo2p + (bo2@Wo + bo).
// R10: REVERT to plain per-stage launches. Evidence: in-kernel grid barriers
// cost ~58us each regardless of implementation (cg::grid.sync R8=886us,
// custom sharded barrier R9=733us, both with ~110MB phantom FETCH from
// cross-XCD coherence) — structural to 8-XCD CDNA4, not fixable in source.
// Keep the mega detour's wins: 11 stages (Wo2p fold killed the M2 GEMM,
// convert-in-staging killed conv passes, c fused into T stages), no memsets.
// launch_bounds(256,4) raises min occupancy to 16 waves/CU for latency-bound
// stages (VGPR<=128).

typedef __bf16 bf16x8 __attribute__((ext_vector_type(8)));
typedef float  f32x4  __attribute__((ext_vector_type(4)));

struct PD { const float* s; void* d; int R, C, Bc, mode, blocks; };
struct PArgs { PD p[20]; int n; };

struct MA {
    const float *x,*bq1,*bo1,*bq2,*bo2,*bo;
    float* out;
    __bf16 *xb,*Wk1t,*Wv1t,*Wq1b,*Wo1t,*Wk2t,*Wv2t,*Wq2b,*Wo2b,*Wot;
    __bf16 *Ktb,*Vtb,*T1b,*M1t,*o1b,*K2tb,*V2tb,*T2b,*Wo2pT,*M2pt;
    float *STf1,*STf2,*kvb1,*kvb2,*c1,*c2p,*bo2p;
    PArgs pa;
    int prepTot;
};

// ---------------- bf16 MFMA GEMM block, C = alpha*(A.B^T) (+bias) ----------
// A: bf16 [M][K] lda (global_load_lds). B: [N][K] ldb k-major — bf16 via
// global_load_lds, or fp32 (BF32=true) converted during staging.
// bz = b*ksplit+ks; b -> (go=b/divq, gi=b%divq). mode: 0=f32, 1=bf16,
// 2=bf16 transposed (C[n][m], ldc=M), 3=f32 atomicAdd. Exact tile multiples.
template<int BM, int BN, bool BF32>
__device__ __forceinline__ void gemm_block(void* smv,
    const __bf16* __restrict__ A, const void* __restrict__ Bv,
    const float* __restrict__ bias, void* __restrict__ Cv,
    int K, int lda, int ldb, int ldc, int divq, int ksplit,
    long aOut, long aIn, long bOut, long bIn, long cOut, long cIn,
    long biasOut, long biasIn, int hasBias, int mode, float alpha,
    int bx, int by, int bz)
{
    constexpr int MT = BM / 32, NT = BN / 32;
    __bf16 (*As)[32] = (__bf16(*)[32])smv;
    __bf16 (*Bs)[32] = (__bf16(*)[32])((char*)smv + BM * 64);

    int b  = bz / ksplit, ks = bz - b * ksplit;
    int go = b / divq,  gi = b - go * divq;
    A += go * aOut + gi * aIn;
    const __bf16* Bb = (const __bf16*)Bv + (BF32 ? 0 : (go * bOut + gi * bIn));
    const float*  Bf = (const float*)Bv + (BF32 ? (go * bOut + gi * bIn) : 0);
    long cBase = go * cOut + gi * cIn;
    if (hasBias) bias += go * biasOut + gi * biasIn;

    int kChunk = K / ksplit;
    int k0 = ks * kChunk, kEnd = k0 + kChunk;

    int bm = by * BM, bn = bx * BN;
    int tid = threadIdx.x, wave = tid >> 6, lane = tid & 63;
    int wm = (wave >> 1) * (BM / 2), wn = (wave & 1) * (BN / 2);
    int mrow = lane & 15, quad = lane >> 4;

    f32x4 acc[MT][NT];
    #pragma unroll
    for (int i = 0; i < MT; ++i)
        #pragma unroll
        for (int j = 0; j < NT; ++j)
            acc[i][j] = f32x4{0.f, 0.f, 0.f, 0.f};

    for (; k0 < kEnd; k0 += 32) {
        __syncthreads();   // prev smem consumers done before overwrite
        #pragma unroll
        for (int t = 0; t < BM / 64; ++t) {
            int c = tid + t * 256;
            int row = c >> 2, kq = c & 3;
            __builtin_amdgcn_global_load_lds(
                (const __attribute__((address_space(1))) void*)
                    (A + (long)(bm + row) * lda + k0 + kq * 8),
                (__attribute__((address_space(3))) void*)&As[row][kq * 8],
                16, 0, 0);
        }
        if (!BF32) {
            #pragma unroll
            for (int t = 0; t < BN / 64; ++t) {
                int c = tid + t * 256;
                int row = c >> 2, kq = c & 3;
                __builtin_amdgcn_global_load_lds(
                    (const __attribute__((address_space(1))) void*)
                        (Bb + (long)(bn + row) * ldb + k0 + kq * 8),
                    (__attribute__((address_space(3))) void*)&Bs[row][kq * 8],
                    16, 0, 0);
            }
        } else {
            // BN=64: 256 threads x 8 fp32 -> bf16
            int row = tid >> 2, cb = (tid & 3) * 8;
            const float* src = Bf + (long)(bn + row) * ldb + k0 + cb;
            float4 f0 = *(const float4*)(src);
            float4 f1 = *(const float4*)(src + 4);
            bf16x8 v = {(__bf16)f0.x, (__bf16)f0.y, (__bf16)f0.z, (__bf16)f0.w,
                        (__bf16)f1.x, (__bf16)f1.y, (__bf16)f1.z, (__bf16)f1.w};
            *(bf16x8*)&Bs[row][cb] = v;
        }
        __syncthreads();

        bf16x8 af[MT], bfv[NT];
        #pragma unroll
        for (int mt = 0; mt < MT; ++mt)
            af[mt] = *(const bf16x8*)&As[wm + mt * 16 + mrow][quad * 8];
        #pragma unroll
        for (int nt = 0; nt < NT; ++nt)
            bfv[nt] = *(const bf16x8*)&Bs[wn + nt * 16 + mrow][quad * 8];
        #pragma unroll
        for (int mt = 0; mt < MT; ++mt)
            #pragma unroll
            for (int nt = 0; nt < NT; ++nt)
                acc[mt][nt] = __builtin_amdgcn_mfma_f32_16x16x32_bf16(
                    af[mt], bfv[nt], acc[mt][nt], 0, 0, 0);
    }

    #pragma unroll
    for (int mt = 0; mt < MT; ++mt) {
        #pragma unroll
        for (int r = 0; r < 4; ++r) {
            int row = bm + wm + mt * 16 + quad * 4 + r;
            #pragma unroll
            for (int nt = 0; nt < NT; ++nt) {
                int col = bn + wn + nt * 16 + mrow;
                float v = acc[mt][nt][r] * alpha;
                if (hasBias) v += bias[col];
                if (mode == 0)
                    ((float*)Cv)[cBase + (long)row * ldc + col] = v;
                else if (mode == 1)
                    ((__bf16*)Cv)[cBase + (long)row * ldc + col] = (__bf16)v;
                else if (mode == 2)
                    ((__bf16*)Cv)[cBase + (long)col * ldc + row] = (__bf16)v;
                else
                    atomicAdd(&((float*)Cv)[cBase + (long)row * ldc + col], v);
            }
        }
    }
}

// ---------------- prep block: converts/transposes/zeros ---------------------
__device__ __forceinline__ void prep_block(const PArgs& a, int bid, void* smv)
{
    int i = 0;
    while (i < a.n && bid >= a.p[i].blocks) { bid -= a.p[i].blocks; ++i; }
    if (i >= a.n) return;
    PD d = a.p[i];
    int t = threadIdx.x;
    if (d.mode == 0) {
        float (*tile)[33] = (float(*)[33])smv;
        int tC = d.C >> 5, tR = d.R >> 5;
        int batch = bid / (tC * tR), rem = bid - batch * (tC * tR);
        int tyo = rem / tC, txo = rem - tyo * tC;
        const float* src = d.s + (long)batch * d.R * d.C;
        __bf16* dst = (__bf16*)d.d + (long)batch * d.R * d.C;
        int tx = t & 31, ty = t >> 5;
        int r0 = tyo * 32, c0 = txo * 32;
        #pragma unroll
        for (int u = 0; u < 4; ++u)
            tile[ty + 8 * u][tx] = src[(long)(r0 + ty + 8 * u) * d.C + c0 + tx];
        __syncthreads();
        #pragma unroll
        for (int u = 0; u < 4; ++u)
            dst[(long)(c0 + ty + 8 * u) * d.R + r0 + tx] = (__bf16)tile[tx][ty + 8 * u];
    } else if (d.mode == 1) {
        long idx = ((long)bid * 256 + t) * 4;
        long total = (long)d.Bc * d.R * d.C;
        if (idx < total) {
            float4 f = *(const float4*)(d.s + idx);
            __bf16* o = (__bf16*)d.d + idx;
            o[0] = (__bf16)f.x; o[1] = (__bf16)f.y;
            o[2] = (__bf16)f.z; o[3] = (__bf16)f.w;
        }
    } else {
        long idx = (long)bid * 256 + t;
        long total = (long)d.Bc * d.R * d.C;
        if (idx < total) {
            float* o = (float*)d.d;
            if (d.mode == 2) o[idx] = d.s[idx];
            else             o[idx] = 0.f;
        }
    }
}

// ---------------- small block: fused r,c (c-only; S read as fp32) -----------
__device__ __forceinline__ void small_block(void* smv,
    const float* __restrict__ STf, const float* __restrict__ bq,
    const __bf16* __restrict__ WoT, const float* __restrict__ boA,
    float* __restrict__ cOut, int ad, int F, long wG, int bid)
{
    int tid = threadIdx.x;
    float* rL  = (float*)smv;
    float* red = (float*)((char*)smv + 4096);
    int g = bid >> 5, slice = bid & 31;
    int nq = F / ad;
    const float* Sg = STf + (long)g * ad * ad;
    for (int f = tid; f < F; f += 256) {
        int q = f / ad, aa = f - q * ad;
        const float* bv = bq + (long)(g * nq + q) * ad;
        const float* Sa = Sg + (long)aa * ad;
        float s = 0.f;
        for (int c = 0; c < ad; c += 4) {
            float4 b4 = *(const float4*)(bv + c);
            float4 s4 = *(const float4*)(Sa + c);
            s += b4.x * s4.x + b4.y * s4.y + b4.z * s4.z + b4.w * s4.w;
        }
        rL[f] = s;
    }
    __syncthreads();
    int dl = tid & 15, fs = tid >> 4;
    int d = slice * 16 + dl;
    int fchunk = F >> 4;
    const __bf16* wrow = WoT + (long)g * wG + (long)d * F;
    float s = 0.f;
    for (int f0 = fs * fchunk; f0 < (fs + 1) * fchunk; f0 += 8) {
        bf16x8 w = *(const bf16x8*)(wrow + f0);
        s += rL[f0]     * (float)w[0] + rL[f0 + 1] * (float)w[1]
           + rL[f0 + 2] * (float)w[2] + rL[f0 + 3] * (float)w[3]
           + rL[f0 + 4] * (float)w[4] + rL[f0 + 5] * (float)w[5]
           + rL[f0 + 6] * (float)w[6] + rL[f0 + 7] * (float)w[7];
    }
    red[tid] = s;
    __syncthreads();
    if (fs == 0) {
        float tsum = s;
        #pragma unroll
        for (int u = 1; u < 16; ++u) tsum += red[u * 16 + dl];
        cOut[(long)g * 512 + d] = boA[(long)g * 512 + d] + tsum;
    }
}

// outp[g][d] = bias[d] + sum_f v[g][f] * WT[d][f]   (F=512)
__device__ __forceinline__ void vecmat_block(void* smv,
    const float* __restrict__ v, const __bf16* __restrict__ WT,
    const float* __restrict__ bias, float* __restrict__ outp, int g, int slice)
{
    float* red2 = (float*)smv;
    int tid = threadIdx.x;
    int dl = tid & 15, fs = tid >> 4;
    int d = slice * 16 + dl;
    const float* vg = v + (long)g * 512;
    const __bf16* wrow = WT + (long)d * 512;
    float s = 0.f;
    for (int f0 = fs * 32; f0 < (fs + 1) * 32; f0 += 8) {
        bf16x8 w = *(const bf16x8*)(wrow + f0);
        s += vg[f0]     * (float)w[0] + vg[f0 + 1] * (float)w[1]
           + vg[f0 + 2] * (float)w[2] + vg[f0 + 3] * (float)w[3]
           + vg[f0 + 4] * (float)w[4] + vg[f0 + 5] * (float)w[5]
           + vg[f0 + 6] * (float)w[6] + vg[f0 + 7] * (float)w[7];
    }
    red2[tid] = s;
    __syncthreads();
    if (fs == 0) {
        float tsum = s;
        #pragma unroll
        for (int u = 1; u < 16; ++u) tsum += red2[u * 16 + dl];
        outp[(long)g * 512 + d] = bias[d] + tsum;
    }
}

// ---------------- stages 0..10 ----------------------------------------------
__device__ __forceinline__ void run_stage(const MA& a, int s, int vb, void* sm)
{
    const float isa1 = 0.08838834764831845f;  // 1/sqrt(128)
    switch (s) {
    case 0: prep_block(a.pa, vb, sm); break;
    case 1:   // KV1 (1024) | Wo2p (512) | bo2p (256)
        if (vb < 1024)
            gemm_block<64,64,false>(sm, a.xb, a.Wk1t, a.kvb1, a.Ktb,
                512, 512, 512, 2048, 1, 1,
                0L, 0L, 65536L, 0L, 262144L, 0L, 128L, 0L, 1, 2, 1.0f,
                vb & 1, (vb >> 1) & 31, vb >> 6);
        else if (vb < 1536) {
            int v = vb - 1024;
            gemm_block<64,64,false>(sm, a.Wo2b, a.Wot, nullptr, a.Wo2pT,
                512, 512, 512, 512, 1, 1,
                262144L, 0L, 0L, 0L, 262144L, 0L, 0L, 0L, 0, 2, 1.0f,
                v & 7, (v >> 3) & 7, v >> 6);
        } else {
            int v = vb - 1536;
            vecmat_block(sm, a.bo2, a.Wot, a.bo, a.bo2p, v & 7, v >> 3);
        }
        break;
    case 2:   // S1^T split-K x8 atomic (256)
        gemm_block<64,64,false>(sm, a.Vtb, a.Ktb, nullptr, a.STf1,
            2048, 2048, 2048, 128, 1, 8,
            262144L, 0L, 262144L, 0L, 16384L, 0L, 0L, 0L, 0, 3, isa1,
            vb & 1, (vb >> 1) & 1, vb >> 2);
        break;
    case 3:   // T1 from fp32 S (1024) | c1 (256)
        if (vb < 1024)
            gemm_block<64,64,true>(sm, a.Wq1b, a.STf1, nullptr, a.T1b,
                128, 128, 128, 1024, 8, 1,
                524288L, 65536L, 16384L, 0L, 524288L, 128L, 0L, 0L, 0, 1, 1.0f,
                vb & 1, (vb >> 1) & 7, vb >> 4);
        else
            small_block(sm, a.STf1, a.bq1, a.Wo1t, a.bo1, a.c1,
                        128, 1024, 524288L, vb - 1024);
        break;
    case 4:   // M1^T (512)
        gemm_block<64,64,false>(sm, a.T1b, a.Wo1t, nullptr, a.M1t,
            1024, 1024, 1024, 512, 1, 1,
            524288L, 0L, 524288L, 0L, 262144L, 0L, 0L, 0L, 0, 2, 1.0f,
            vb & 7, (vb >> 3) & 7, vb >> 6);
        break;
    case 5:   // o1 = x.M1 + c1 (512, 128^2)
        gemm_block<128,128,false>(sm, a.xb, a.M1t, a.c1, a.o1b,
            512, 512, 512, 512, 1, 1,
            0L, 0L, 262144L, 0L, 1048576L, 0L, 512L, 0L, 1, 1, 1.0f,
            vb & 3, (vb >> 2) & 15, vb >> 6);
        break;
    case 6:   // KV2 fused (512)
        gemm_block<64,64,false>(sm, a.o1b, a.Wk2t, a.kvb2, a.K2tb,
            512, 512, 512, 2048, 8, 1,
            0L, 1048576L, 262144L, 32768L, 1048576L, 131072L, 512L, 64L,
            1, 2, 1.0f, 0, vb & 31, vb >> 5);
        break;
    case 7:   // S2^T split-K x16 atomic (128)
        gemm_block<64,64,false>(sm, a.V2tb, a.K2tb, nullptr, a.STf2,
            2048, 2048, 2048, 64, 1, 16,
            131072L, 0L, 131072L, 0L, 4096L, 0L, 0L, 0L, 0, 3, 0.125f,
            0, 0, vb);
        break;
    case 8:   // T2 from fp32 S (512) | c2p (256)
        if (vb < 512)
            gemm_block<64,64,true>(sm, a.Wq2b, a.STf2, nullptr, a.T2b,
                64, 64, 64, 512, 8, 1,
                262144L, 32768L, 4096L, 0L, 262144L, 64L, 0L, 0L, 0, 1, 1.0f,
                0, vb & 7, vb >> 3);
        else
            small_block(sm, a.STf2, a.bq2, a.Wo2pT, a.bo2p, a.c2p,
                        64, 512, 262144L, vb - 512);
        break;
    case 9:   // M2p^T = (T2.Wo2p)^T (512)
        gemm_block<64,64,false>(sm, a.T2b, a.Wo2pT, nullptr, a.M2pt,
            512, 512, 512, 512, 1, 1,
            262144L, 0L, 262144L, 0L, 262144L, 0L, 0L, 0L, 0, 2, 1.0f,
            vb & 7, (vb >> 3) & 7, vb >> 6);
        break;
    default:  // 10: out = o1.M2p + c2p (512, 128^2)
        gemm_block<128,128,false>(sm, a.o1b, a.M2pt, a.c2p, a.out,
            512, 512, 512, 512, 1, 1,
            1048576L, 0L, 262144L, 0L, 1048576L, 0L, 512L, 0L, 1, 0, 1.0f,
            vb & 3, (vb >> 2) & 15, vb >> 6);
        break;
    }
}

__global__ __launch_bounds__(256, 4) void stage_kernel(MA a, int stage)
{
    __shared__ __align__(16) unsigned char smem[16384];
    run_stage(a, stage, blockIdx.x, smem);
}

extern "C" void kernel_launch(void* const* d_in, const int* in_sizes, int n_in,
                              void* d_out, int out_size, void* d_ws, size_t ws_size,
                              hipStream_t stream)
{
    MA ma;
    ma.x   = (const float*)d_in[0];
    const float* Wq1 = (const float*)d_in[1];  ma.bq1 = (const float*)d_in[2];
    const float* Wk1 = (const float*)d_in[3];  const float* bk1 = (const float*)d_in[4];
    const float* Wv1 = (const float*)d_in[5];  const float* bv1 = (const float*)d_in[6];
    const float* Wo1 = (const float*)d_in[7];  ma.bo1 = (const float*)d_in[8];
    const float* Wq2 = (const float*)d_in[9];  ma.bq2 = (const float*)d_in[10];
    const float* Wk2 = (const float*)d_in[11]; const float* bk2 = (const float*)d_in[12];
    const float* Wv2 = (const float*)d_in[13]; const float* bv2 = (const float*)d_in[14];
    const float* Wo2 = (const float*)d_in[15]; ma.bo2 = (const float*)d_in[16];
    const float* Wo  = (const float*)d_in[17]; ma.bo  = (const float*)d_in[18];
    ma.out = (float*)d_out;
    (void)in_sizes; (void)n_in; (void)out_size; (void)ws_size;

    __bf16* wb = (__bf16*)d_ws;
    long o = 0;
    ma.xb    = wb + o; o += 1048576;
    ma.Wk1t  = wb + o; o += 524288;
    ma.Wv1t  = wb + o; o += 524288;
    ma.Wq1b  = wb + o; o += 4194304;
    ma.Wo1t  = wb + o; o += 4194304;
    ma.Wk2t  = wb + o; o += 262144;
    ma.Wv2t  = wb + o; o += 262144;
    ma.Wq2b  = wb + o; o += 2097152;
    ma.Wo2b  = wb + o; o += 2097152;   // Wo2 bf16 flat [g][512f][512d]
    ma.Wot   = wb + o; o += 262144;    // Wo^T [512e][512d]
    ma.Ktb   = wb + o; o += 2097152;   // K1^T [g][128][2048]
    ma.Vtb   = wb + o; o += 2097152;
    ma.T1b   = wb + o; o += 4194304;
    ma.M1t   = wb + o; o += 2097152;
    ma.o1b   = wb + o; o += 8388608;
    ma.K2tb  = ma.Ktb;                 // alias: K2^T [g][64][2048]
    ma.V2tb  = ma.Ktb + 1048576;       // alias: V2^T
    ma.T2b   = wb + o; o += 2097152;
    ma.Wo2pT = wb + o; o += 2097152;   // (Wo2@Wo)^T [g][512e][512f]
    ma.M2pt  = wb + o; o += 2097152;
    float* wf = (float*)(wb + o);
    long p = 0;
    ma.STf1 = wf + p; p += 131072;
    ma.STf2 = wf + p; p += 32768;
    ma.kvb1 = wf + p; p += 2048;
    ma.kvb2 = wf + p; p += 1024;
    ma.c1   = wf + p; p += 4096;
    ma.c2p  = wf + p; p += 4096;
    ma.bo2p = wf + p; p += 4096;

    int nd = 0, totB = 0;
    auto add = [&](const float* s, void* d, int R, int C, int Bc, int mode) {
        int blocks;
        long total = (long)Bc * R * C;
        if (mode == 0) blocks = Bc * (R >> 5) * (C >> 5);
        else if (mode == 1) blocks = (int)(total / 1024);
        else blocks = (int)((total + 255) / 256);
        ma.pa.p[nd] = PD{s, d, R, C, Bc, mode, blocks};
        ++nd; totB += blocks;
    };
    add(ma.x, ma.xb,   2048, 512, 1, 1);
    add(Wq1,  ma.Wq1b, 512, 128, 64, 1);
    add(Wq2,  ma.Wq2b, 512, 64, 64, 1);
    add(Wo2,  ma.Wo2b, 512, 512, 8, 1);
    add(Wk1,  ma.Wk1t, 512, 128, 8, 0);
    add(Wv1,  ma.Wv1t, 512, 128, 8, 0);
    add(Wo1,  ma.Wo1t, 1024, 512, 8, 0);
    add(Wk2,  ma.Wk2t, 512, 64, 8, 0);
    add(Wv2,  ma.Wv2t, 512, 64, 8, 0);
    add(Wo,   ma.Wot,  512, 512, 1, 0);
    add(bk1,  ma.kvb1,        1, 1024, 1, 2);
    add(bv1,  ma.kvb1 + 1024, 1, 1024, 1, 2);
    add(bk2,  ma.kvb2,        1, 512, 1, 2);
    add(bv2,  ma.kvb2 + 512,  1, 512, 1, 2);
    add(nullptr, ma.STf1, 1, 131072, 1, 4);
    add(nullptr, ma.STf2, 1, 32768, 1, 4);
    ma.pa.n = nd;
    ma.prepTot = totB;

    const int counts[11] = {ma.prepTot, 1792, 256, 1280, 512, 512, 512, 128,
                            768, 512, 512};
    for (int s = 0; s < 11; ++s)
        stage_kernel<<<dim3(counts[s]), dim3(256), 0, stream>>>(ma, s);
}